// Round 2
// baseline (1045.880 us; speedup 1.0000x reference)
//
#include <hip/hip_runtime.h>
#include <hip/hip_bf16.h>
#include <stdint.h>

// Problem constants
#define BB   4
#define NS   10000
#define NT   10000
#define EE   160000
#define KK   16
#define DD   128

typedef short s8v  __attribute__((ext_vector_type(8)));   // 8 bf16 (4 VGPRs)
typedef float f4v  __attribute__((ext_vector_type(4)));   // 4 fp32 acc

static __device__ __forceinline__ float bf2f(unsigned short u) {
    union { unsigned int i; float f; } v; v.i = ((unsigned int)u) << 16; return v.f;
}
static __device__ __forceinline__ unsigned short f2bf(float f) {
    union { float f; unsigned int i; } v; v.f = f;
    unsigned int x = v.i;
    unsigned int r = x + 0x7fffu + ((x >> 16) & 1u);   // round-to-nearest-even
    return (unsigned short)(r >> 16);
}

// B-fragment (fp32 source): lane holds W[32c+8q+j][16t+np], j=0..7
static __device__ __forceinline__ s8v load_bfrag_f32(const float* __restrict__ W,
                                                     int c, int t, int q, int np) {
    s8v r;
    const float* p = W + (32 * c + 8 * q) * DD + 16 * t + np;
#pragma unroll
    for (int j = 0; j < 8; ++j) r[j] = (short)f2bf(p[j * DD]);
    return r;
}

// A-fragment (fp32 source, contiguous 8 floats)
static __device__ __forceinline__ s8v load_afrag_f32(const float* __restrict__ p) {
    s8v r;
#pragma unroll
    for (int j = 0; j < 8; ++j) r[j] = (short)f2bf(p[j]);
    return r;
}

// ---------------------------------------------------------------------------
// K1: s_proj = src @ W_s2e -> out_s (bf16) ; t_proj = tgt @ W_t2e -> out_t
// ---------------------------------------------------------------------------
__global__ __launch_bounds__(256, 2)
void proj_kernel(const float* __restrict__ src,
                 const float* __restrict__ tgt,
                 const float* __restrict__ Ws,
                 const float* __restrict__ Wt,
                 unsigned short* __restrict__ out_s,
                 unsigned short* __restrict__ out_t)
{
    const int lane = threadIdx.x & 63;
    const int wave = threadIdx.x >> 6;
    const int np = lane & 15, q = lane >> 4;

    const float* X; const float* W; unsigned short* O;
    if (blockIdx.y == 0) { X = src; W = Ws; O = out_s; }
    else                 { X = tgt; W = Wt; O = out_t; }

    s8v bw[4][8];
#pragma unroll
    for (int c = 0; c < 4; ++c)
#pragma unroll
        for (int t = 0; t < 8; ++t) bw[c][t] = load_bfrag_f32(W, c, t, q, np);

    const int NTILES = (BB * NS) / 16;      // 2500
    const int nw = gridDim.x * 4;
    for (int tile = blockIdx.x * 4 + wave; tile < NTILES; tile += nw) {
        const float* abase = X + (size_t)(tile * 16 + np) * DD + 8 * q;
        s8v a[4];
#pragma unroll
        for (int c = 0; c < 4; ++c) a[c] = load_afrag_f32(abase + 32 * c);
        f4v acc[8];
        const f4v zero = {0.f, 0.f, 0.f, 0.f};
#pragma unroll
        for (int t = 0; t < 8; ++t) acc[t] = zero;
#pragma unroll
        for (int c = 0; c < 4; ++c)
#pragma unroll
            for (int t = 0; t < 8; ++t)
                acc[t] = __builtin_amdgcn_mfma_f32_16x16x32_bf16(a[c], bw[c][t], acc[t], 0, 0, 0);
        // C layout: row = 4q+r, col = 16t+np
        const size_t orow = (size_t)(tile * 16 + 4 * q) * DD;
#pragma unroll
        for (int r = 0; r < 4; ++r)
#pragma unroll
            for (int t = 0; t < 8; ++t)
                O[orow + (size_t)r * DD + 16 * t + np] = f2bf(acc[t][r]);
    }
}

// ---------------------------------------------------------------------------
// K2: out0 = bond + LN(silu(bond@W_e2e + s_proj[src_order] + t_proj[tgt_order]))
//     optionally writes d_bond (bf16) to ws
// ---------------------------------------------------------------------------
__global__ __launch_bounds__(256, 2)
void bond_kernel(const float* __restrict__ bond,
                 const float* __restrict__ We,
                 const unsigned short* __restrict__ sproj,
                 const unsigned short* __restrict__ tproj,
                 const int* __restrict__ src_order,
                 const int* __restrict__ tgt_order,
                 const float* __restrict__ g1,
                 const float* __restrict__ b1,
                 float* __restrict__ out0,
                 unsigned short* __restrict__ dbond)
{
    const int lane = threadIdx.x & 63;
    const int wave = threadIdx.x >> 6;
    const int np = lane & 15, q = lane >> 4;
    const int b = blockIdx.y;

    s8v bw[4][8];
#pragma unroll
    for (int c = 0; c < 4; ++c)
#pragma unroll
        for (int t = 0; t < 8; ++t) bw[c][t] = load_bfrag_f32(We, c, t, q, np);

    float gv[8], bv[8];
#pragma unroll
    for (int t = 0; t < 8; ++t) { gv[t] = g1[16 * t + np]; bv[t] = b1[16 * t + np]; }

    const int TPB = EE / 16;                 // 10000 tiles per batch
    const int nw = gridDim.x * 4;
    for (int tile = blockIdx.x * 4 + wave; tile < TPB; tile += nw) {
        const int e0 = tile * 16;
        const size_t rowbase = ((size_t)b * EE + e0) * DD;

        const float* abase = bond + rowbase + (size_t)np * DD + 8 * q;
        s8v a[4];
#pragma unroll
        for (int c = 0; c < 4; ++c) a[c] = load_afrag_f32(abase + 32 * c);

        f4v acc[8];
        const f4v zero = {0.f, 0.f, 0.f, 0.f};
#pragma unroll
        for (int t = 0; t < 8; ++t) acc[t] = zero;
#pragma unroll
        for (int c = 0; c < 4; ++c)
#pragma unroll
            for (int t = 0; t < 8; ++t)
                acc[t] = __builtin_amdgcn_mfma_f32_16x16x32_bf16(a[c], bw[c][t], acc[t], 0, 0, 0);

        // gathers + silu, stats (x stored back into acc)
        float s1[4] = {0.f, 0.f, 0.f, 0.f};
        float s2[4] = {0.f, 0.f, 0.f, 0.f};
#pragma unroll
        for (int r = 0; r < 4; ++r) {
            const int e = e0 + 4 * q + r;
            const int se = src_order[e];
            const int te = tgt_order[e];
            const unsigned short* sp = sproj + ((size_t)b * NS + se) * DD + np;
            const unsigned short* tp = tproj + ((size_t)b * NT + te) * DD + np;
#pragma unroll
            for (int t = 0; t < 8; ++t) {
                float d = acc[t][r] + bf2f(sp[16 * t]) + bf2f(tp[16 * t]);
                float s = 1.0f / (1.0f + __expf(-d));
                float xv = d * s;
                acc[t][r] = xv;
                s1[r] += xv;
                s2[r] += xv * xv;
            }
        }
        // reduce across the 16 lanes of each quad (they span all 128 cols)
#pragma unroll
        for (int off = 1; off < 16; off <<= 1) {
#pragma unroll
            for (int r = 0; r < 4; ++r) {
                s1[r] += __shfl_xor(s1[r], off, 16);
                s2[r] += __shfl_xor(s2[r], off, 16);
            }
        }
        float mean[4], rstd[4];
#pragma unroll
        for (int r = 0; r < 4; ++r) {
            mean[r] = s1[r] * (1.0f / 128.0f);
            float var = s2[r] * (1.0f / 128.0f) - mean[r] * mean[r];
            rstd[r] = rsqrtf(var + 1e-5f);
        }
        // write out0 (= bond + y, fp32) and optional d_bond (bf16)
        const size_t crow = rowbase + (size_t)(4 * q) * DD;
#pragma unroll
        for (int r = 0; r < 4; ++r) {
            const size_t ro = crow + (size_t)r * DD;
#pragma unroll
            for (int t = 0; t < 8; ++t) {
                float y = (acc[t][r] - mean[r]) * rstd[r] * gv[t] + bv[t];
                const int col = 16 * t + np;
                out0[ro + col] = bond[ro + col] + y;
                if (dbond) dbond[ro + col] = f2bf(y);
            }
        }
    }
}

// ---------------------------------------------------------------------------
// K3: bond_reduce = (1/16) sum_k coef * d_bond[edge_order]; d_tgt = br@W_e2t +
//     tgt@W_t2t; out2 = tgt + LN(silu(d_tgt)).  d_bond from ws, or out0-bond.
// ---------------------------------------------------------------------------
__global__ __launch_bounds__(256, 2)
void tgt_kernel(const unsigned short* __restrict__ dbond,   // bf16 ws, or null
                const float* __restrict__ out0,             // fallback minuend
                const float* __restrict__ bond,             // fallback subtrahend
                const float* __restrict__ tgt,
                const float* __restrict__ We2t,
                const float* __restrict__ Wt2t,
                const float* __restrict__ coef,
                const int* __restrict__ edge_order,
                const float* __restrict__ g2,
                const float* __restrict__ b2,
                float* __restrict__ out2)
{
    const int lane = threadIdx.x & 63;
    const int wave = threadIdx.x >> 6;
    const int np = lane & 15, q = lane >> 4;
    const int b = blockIdx.y;

    const int tile = blockIdx.x * 4 + wave;
    if (tile >= NT / 16) return;
    const int t0 = tile * 16;
    const int myrow = t0 + np;                 // A-layout row (m = lane&15)

    // gather-accumulate in A-fragment element layout: cols 32c+8q+j
    float ad[4][8];
#pragma unroll
    for (int c = 0; c < 4; ++c)
#pragma unroll
        for (int j = 0; j < 8; ++j) ad[c][j] = 0.f;

    for (int k = 0; k < KK; ++k) {
        const int eo = edge_order[myrow * KK + k];
        const float cf = coef[myrow * KK + k];
        if (dbond) {
            const unsigned short* p = dbond + ((size_t)b * EE + eo) * DD + 8 * q;
#pragma unroll
            for (int c = 0; c < 4; ++c)
#pragma unroll
                for (int j = 0; j < 8; ++j)
                    ad[c][j] += cf * bf2f(p[32 * c + j]);
        } else {
            const float* p0 = out0 + ((size_t)b * EE + eo) * DD + 8 * q;
            const float* p1 = bond + ((size_t)b * EE + eo) * DD + 8 * q;
#pragma unroll
            for (int c = 0; c < 4; ++c)
#pragma unroll
                for (int j = 0; j < 8; ++j)
                    ad[c][j] += cf * (p0[32 * c + j] - p1[32 * c + j]);
        }
    }
    // to bf16 A-frags (apply 1/K)
    s8v adf[4];
#pragma unroll
    for (int c = 0; c < 4; ++c)
#pragma unroll
        for (int j = 0; j < 8; ++j) adf[c][j] = (short)f2bf(ad[c][j] * (1.0f / 16.0f));

    const float* tb = tgt + ((size_t)b * NT + myrow) * DD + 8 * q;
    s8v at[4];
#pragma unroll
    for (int c = 0; c < 4; ++c) at[c] = load_afrag_f32(tb + 32 * c);

    f4v acc[8];
    const f4v zero = {0.f, 0.f, 0.f, 0.f};
#pragma unroll
    for (int t = 0; t < 8; ++t) acc[t] = zero;
#pragma unroll
    for (int c = 0; c < 4; ++c) {
#pragma unroll
        for (int t = 0; t < 8; ++t) {
            acc[t] = __builtin_amdgcn_mfma_f32_16x16x32_bf16(adf[c], load_bfrag_f32(We2t, c, t, q, np), acc[t], 0, 0, 0);
            acc[t] = __builtin_amdgcn_mfma_f32_16x16x32_bf16(at[c],  load_bfrag_f32(Wt2t, c, t, q, np), acc[t], 0, 0, 0);
        }
    }

    // epilogue: silu + LN + tgt add
    float gv[8], bv[8];
#pragma unroll
    for (int t = 0; t < 8; ++t) { gv[t] = g2[16 * t + np]; bv[t] = b2[16 * t + np]; }

    float s1[4] = {0.f, 0.f, 0.f, 0.f};
    float s2[4] = {0.f, 0.f, 0.f, 0.f};
#pragma unroll
    for (int r = 0; r < 4; ++r)
#pragma unroll
        for (int t = 0; t < 8; ++t) {
            float d = acc[t][r];
            float s = 1.0f / (1.0f + __expf(-d));
            float xv = d * s;
            acc[t][r] = xv;
            s1[r] += xv;
            s2[r] += xv * xv;
        }
#pragma unroll
    for (int off = 1; off < 16; off <<= 1) {
#pragma unroll
        for (int r = 0; r < 4; ++r) {
            s1[r] += __shfl_xor(s1[r], off, 16);
            s2[r] += __shfl_xor(s2[r], off, 16);
        }
    }
    float mean[4], rstd[4];
#pragma unroll
    for (int r = 0; r < 4; ++r) {
        mean[r] = s1[r] * (1.0f / 128.0f);
        float var = s2[r] * (1.0f / 128.0f) - mean[r] * mean[r];
        rstd[r] = rsqrtf(var + 1e-5f);
    }
    const size_t crow = ((size_t)b * NT + t0 + 4 * q) * DD;
#pragma unroll
    for (int r = 0; r < 4; ++r) {
        const size_t ro = crow + (size_t)r * DD;
#pragma unroll
        for (int t = 0; t < 8; ++t) {
            float y = (acc[t][r] - mean[r]) * rstd[r] * gv[t] + bv[t];
            const int col = 16 * t + np;
            out2[ro + col] = tgt[ro + col] + y;
        }
    }
}

// K4: out1 = src (plain fp32 copy)
__global__ void copy_kernel(const uint4* __restrict__ s, uint4* __restrict__ d, int n) {
    int i = blockIdx.x * blockDim.x + threadIdx.x;
    const int st = gridDim.x * blockDim.x;
    for (; i < n; i += st) d[i] = s[i];
}

extern "C" void kernel_launch(void* const* d_in, const int* in_sizes, int n_in,
                              void* d_out, int out_size, void* d_ws, size_t ws_size,
                              hipStream_t stream)
{
    const float* bond = (const float*)d_in[0];
    const float* src  = (const float*)d_in[1];
    const float* tgt  = (const float*)d_in[2];
    const float* Ws2e = (const float*)d_in[3];
    const float* Wt2e = (const float*)d_in[4];
    const float* We2e = (const float*)d_in[5];
    const float* g1   = (const float*)d_in[6];
    const float* b1   = (const float*)d_in[7];
    const float* We2t = (const float*)d_in[8];
    const float* Wt2t = (const float*)d_in[9];
    const float* g2   = (const float*)d_in[10];
    const float* b2   = (const float*)d_in[11];
    const float* coef = (const float*)d_in[12];
    const int* src_order  = (const int*)d_in[13];
    const int* tgt_order  = (const int*)d_in[14];
    const int* edge_order = (const int*)d_in[15];

    float* out0 = (float*)d_out;
    float* out1 = out0 + (size_t)BB * EE * DD;   // src slot; staging: s_proj bf16
    float* out2 = out1 + (size_t)BB * NS * DD;   // tgt slot; staging: t_proj bf16

    unsigned short* sproj = (unsigned short*)out1;   // 10.24 MB bf16 in 20.5 MB slot
    unsigned short* tproj = (unsigned short*)out2;

    const size_t dbond_bytes = (size_t)BB * EE * DD * 2;   // 163.84 MB
    unsigned short* dbond = (ws_size >= dbond_bytes) ? (unsigned short*)d_ws : nullptr;

    // K1: projections into bf16 staging (inside out1/out2 slots)
    proj_kernel<<<dim3(128, 2), 256, 0, stream>>>(src, tgt, Ws2e, Wt2e, sproj, tproj);

    // K2: bond update, writes out0 (fp32) and optionally ws d_bond (bf16)
    bond_kernel<<<dim3(128, BB), 256, 0, stream>>>(bond, We2e, sproj, tproj,
                                                   src_order, tgt_order, g1, b1,
                                                   out0, dbond);

    // K3: target update (overwrites out2 after K2 consumed t_proj)
    tgt_kernel<<<dim3(157, BB), 256, 0, stream>>>(dbond, out0, bond, tgt, We2t, Wt2t,
                                                  coef, edge_order, g2, b2, out2);

    // K4: out1 = src copy (after K2 consumed s_proj staging)
    copy_kernel<<<dim3(1024), 256, 0, stream>>>((const uint4*)src, (uint4*)out1,
                                                (int)((size_t)BB * NS * DD / 4));
}